// Round 1
// baseline (366.866 us; speedup 1.0000x reference)
//
#include <hip/hip_runtime.h>

// Masking: zero the k smallest mask_weights positions in weights.
// Exact selection on composite key (order_preserving_u32(mask) << 32) | idx,
// matching jax.lax.top_k's lower-index-first tie-breaking.

#define NBINS 2048
#define CAP1 (1u << 22)   // candidate buffer (bin==b1); expected ~hundreds, worst realistic ~1.5M
#define CAP2 65536u       // second-level candidates (b1,b2 match); expected ~1

__device__ unsigned long long g_k;
__device__ long long          g_b1;      // -1 => k==0 (nothing zeroed)
__device__ unsigned long long g_rem1;    // 1-based rank within bin b1
__device__ unsigned int       g_hist1[NBINS];
__device__ unsigned int       g_hist2[NBINS];
__device__ unsigned int       g_count1;
__device__ unsigned int       g_count2;
__device__ unsigned long long g_kstar_excl; // zero iff composite key < this
__device__ unsigned int       g_cand_u[CAP1];
__device__ unsigned int       g_cand_i[CAP1];
__device__ unsigned long long g_cand2[CAP2];

static __device__ __forceinline__ unsigned int xf(unsigned int b) {
  // monotonic float->uint transform (asc float order == asc unsigned order)
  return b ^ ((unsigned int)((int)b >> 31) | 0x80000000u);
}

__global__ __launch_bounds__(256) void k_init(const int* __restrict__ mp, long long n) {
  int t = threadIdx.x;
  for (int i = t; i < NBINS; i += 256) { g_hist1[i] = 0; g_hist2[i] = 0; }
  if (t == 0) {
    long long m = (long long)(*mp);
    long long k = (n * (100 - m)) / 100;   // exact for mp=50; truncation matches int()
    if (k < 0) k = 0;
    if (k > n) k = n;
    g_k = (unsigned long long)k;
    g_count1 = 0;
    g_count2 = 0;
    g_kstar_excl = 0;
    g_b1 = -1;
    g_rem1 = 0;
  }
}

__global__ __launch_bounds__(256) void hist1_kernel(const unsigned int* __restrict__ mb,
                                                    long long n4, long long n) {
  __shared__ unsigned int sh[4 * NBINS];  // per-wave replicas to damp LDS atomic contention
  const int t = threadIdx.x;
  for (int i = t; i < 4 * NBINS; i += 256) sh[i] = 0;
  __syncthreads();
  unsigned int* h = &sh[(t >> 6) * NBINS];
  const long long stride = (long long)gridDim.x * 256;
  const uint4* mb4 = (const uint4*)mb;
  for (long long i = (long long)blockIdx.x * 256 + t; i < n4; i += stride) {
    uint4 v = mb4[i];
    atomicAdd(&h[xf(v.x) >> 21], 1u);
    atomicAdd(&h[xf(v.y) >> 21], 1u);
    atomicAdd(&h[xf(v.z) >> 21], 1u);
    atomicAdd(&h[xf(v.w) >> 21], 1u);
  }
  if (blockIdx.x == 0) {  // scalar tail
    long long rs = n4 << 2;
    if ((long long)t < n - rs) atomicAdd(&h[xf(mb[rs + t]) >> 21], 1u);
  }
  __syncthreads();
  for (int i = t; i < NBINS; i += 256) {
    unsigned int s = sh[i] + sh[i + NBINS] + sh[i + 2 * NBINS] + sh[i + 3 * NBINS];
    if (s) atomicAdd(&g_hist1[i], s);
  }
}

__global__ __launch_bounds__(256) void select1_kernel() {
  __shared__ unsigned long long tsum[256];
  __shared__ long long s_bin;
  __shared__ unsigned long long s_rem;
  const int t = threadIdx.x;
  unsigned long long k = g_k;
  if (k == 0) return;  // uniform exit; g_b1 stays -1
  unsigned int local[8];
  unsigned long long s = 0;
#pragma unroll
  for (int j = 0; j < 8; j++) { local[j] = g_hist1[t * 8 + j]; s += local[j]; }
  tsum[t] = s;
  __syncthreads();
  for (int off = 1; off < 256; off <<= 1) {
    unsigned long long v = (t >= off) ? tsum[t - off] : 0ull;
    __syncthreads();
    tsum[t] += v;
    __syncthreads();
  }
  unsigned long long incl = tsum[t], excl = incl - s;
  if (excl < k && k <= incl) {
    unsigned long long cum = excl;
#pragma unroll
    for (int j = 0; j < 8; j++) {
      if (cum + local[j] >= k) { s_bin = t * 8 + j; s_rem = k - cum; break; }
      cum += local[j];
    }
  }
  __syncthreads();
  if (t == 0) { g_b1 = s_bin; g_rem1 = s_rem; }
}

__global__ __launch_bounds__(256) void pass2_kernel(const unsigned int* __restrict__ mb,
                                                    const float* __restrict__ w,
                                                    float* __restrict__ out,
                                                    long long n4, long long n) {
  __shared__ unsigned int sh2[NBINS];
  const int t = threadIdx.x;
  for (int i = t; i < NBINS; i += 256) sh2[i] = 0;
  __syncthreads();
  const long long b1 = g_b1;
  const long long stride = (long long)gridDim.x * 256;
  const uint4*  mb4 = (const uint4*)mb;
  const float4* w4  = (const float4*)w;
  float4*       o4  = (float4*)out;
  for (long long i = (long long)blockIdx.x * 256 + t; i < n4; i += stride) {
    uint4  mv = mb4[i];
    float4 wv = w4[i];
    unsigned int u0 = xf(mv.x), u1 = xf(mv.y), u2 = xf(mv.z), u3 = xf(mv.w);
    float4 o;
    o.x = ((long long)(u0 >> 21) < b1) ? 0.0f : wv.x;
    o.y = ((long long)(u1 >> 21) < b1) ? 0.0f : wv.y;
    o.z = ((long long)(u2 >> 21) < b1) ? 0.0f : wv.z;
    o.w = ((long long)(u3 >> 21) < b1) ? 0.0f : wv.w;
    o4[i] = o;
    long long base = i << 2;
    if ((long long)(u0 >> 21) == b1) {
      unsigned int s = atomicAdd(&g_count1, 1u);
      if (s < CAP1) { g_cand_u[s] = u0; g_cand_i[s] = (unsigned int)(base + 0); }
      atomicAdd(&sh2[(u0 >> 10) & (NBINS - 1)], 1u);
    }
    if ((long long)(u1 >> 21) == b1) {
      unsigned int s = atomicAdd(&g_count1, 1u);
      if (s < CAP1) { g_cand_u[s] = u1; g_cand_i[s] = (unsigned int)(base + 1); }
      atomicAdd(&sh2[(u1 >> 10) & (NBINS - 1)], 1u);
    }
    if ((long long)(u2 >> 21) == b1) {
      unsigned int s = atomicAdd(&g_count1, 1u);
      if (s < CAP1) { g_cand_u[s] = u2; g_cand_i[s] = (unsigned int)(base + 2); }
      atomicAdd(&sh2[(u2 >> 10) & (NBINS - 1)], 1u);
    }
    if ((long long)(u3 >> 21) == b1) {
      unsigned int s = atomicAdd(&g_count1, 1u);
      if (s < CAP1) { g_cand_u[s] = u3; g_cand_i[s] = (unsigned int)(base + 3); }
      atomicAdd(&sh2[(u3 >> 10) & (NBINS - 1)], 1u);
    }
  }
  if (blockIdx.x == 0) {  // scalar tail
    long long rs = n4 << 2;
    long long i = rs + t;
    if (i < n) {
      unsigned int u = xf(mb[i]);
      out[i] = ((long long)(u >> 21) < b1) ? 0.0f : w[i];
      if ((long long)(u >> 21) == b1) {
        unsigned int s = atomicAdd(&g_count1, 1u);
        if (s < CAP1) { g_cand_u[s] = u; g_cand_i[s] = (unsigned int)i; }
        atomicAdd(&sh2[(u >> 10) & (NBINS - 1)], 1u);
      }
    }
  }
  __syncthreads();
  for (int i = t; i < NBINS; i += 256)
    if (sh2[i]) atomicAdd(&g_hist2[i], sh2[i]);
}

__global__ __launch_bounds__(256) void finalize_kernel() {
  __shared__ unsigned long long tsum[256];
  __shared__ long long s_b2;
  __shared__ unsigned long long s_rem2;
  const int t = threadIdx.x;
  long long b1 = g_b1;
  if (b1 < 0) return;  // k==0: kstar stays 0
  // find b2: bin of rank g_rem1 within hist2
  {
    unsigned long long k = g_rem1;
    unsigned int local[8];
    unsigned long long s = 0;
#pragma unroll
    for (int j = 0; j < 8; j++) { local[j] = g_hist2[t * 8 + j]; s += local[j]; }
    tsum[t] = s;
    __syncthreads();
    for (int off = 1; off < 256; off <<= 1) {
      unsigned long long v = (t >= off) ? tsum[t - off] : 0ull;
      __syncthreads();
      tsum[t] += v;
      __syncthreads();
    }
    unsigned long long incl = tsum[t], excl = incl - s;
    if (excl < k && k <= incl) {
      unsigned long long cum = excl;
#pragma unroll
      for (int j = 0; j < 8; j++) {
        if (cum + local[j] >= k) { s_b2 = t * 8 + j; s_rem2 = k - cum; break; }
        cum += local[j];
      }
    }
    __syncthreads();
  }
  const unsigned int b2 = (unsigned int)s_b2;
  const unsigned int C = (g_count1 < CAP1) ? g_count1 : CAP1;
  for (unsigned int i = t; i < C; i += 256) {
    unsigned int u = g_cand_u[i];
    if (((u >> 10) & (NBINS - 1)) == b2) {
      unsigned int slot = atomicAdd(&g_count2, 1u);
      if (slot < CAP2) g_cand2[slot] = ((unsigned long long)u << 32) | (unsigned long long)g_cand_i[i];
    }
  }
  __threadfence();
  __syncthreads();
  unsigned int c2 = atomicAdd(&g_count2, 0u);  // atomic read (L2-coherent)
  const unsigned int C2 = (c2 < CAP2) ? c2 : CAP2;
  const unsigned long long rem2 = s_rem2;
  // rank-select the rem2-th smallest composite key (keys unique)
  for (unsigned int i = t; i < C2; i += 256) {
    unsigned long long key = g_cand2[i];
    unsigned long long cnt = 0;
    for (unsigned int j = 0; j < C2; j++) cnt += (g_cand2[j] < key) ? 1ull : 0ull;
    if (cnt + 1 == rem2) g_kstar_excl = key + 1;  // exclusive threshold
  }
}

__global__ __launch_bounds__(256) void fixup_kernel(float* __restrict__ out) {
  const unsigned long long kstar = g_kstar_excl;
  const unsigned int C = (g_count1 < CAP1) ? g_count1 : CAP1;
  const long long stride = (long long)gridDim.x * blockDim.x;
  for (long long i = (long long)blockIdx.x * blockDim.x + threadIdx.x; i < (long long)C; i += stride) {
    unsigned int idx = g_cand_i[i];
    unsigned long long key = ((unsigned long long)g_cand_u[i] << 32) | (unsigned long long)idx;
    if (key < kstar) out[idx] = 0.0f;
  }
}

extern "C" void kernel_launch(void* const* d_in, const int* in_sizes, int n_in,
                              void* d_out, int out_size, void* d_ws, size_t ws_size,
                              hipStream_t stream) {
  const float*        w  = (const float*)d_in[0];
  const unsigned int* mb = (const unsigned int*)d_in[1];  // mask_weights bits
  const int*          mp = (const int*)d_in[2];
  float* out = (float*)d_out;
  const long long n  = (long long)in_sizes[0];
  const long long n4 = n >> 2;

  int blocks = (int)((n4 + 255) / 256);
  if (blocks > 2048) blocks = 2048;
  if (blocks < 1) blocks = 1;

  k_init<<<1, 256, 0, stream>>>(mp, n);
  hist1_kernel<<<blocks, 256, 0, stream>>>(mb, n4, n);
  select1_kernel<<<1, 256, 0, stream>>>();
  pass2_kernel<<<blocks, 256, 0, stream>>>(mb, w, out, n4, n);
  finalize_kernel<<<1, 256, 0, stream>>>();
  fixup_kernel<<<256, 256, 0, stream>>>(out);
}